// Round 5
// baseline (2116.103 us; speedup 1.0000x reference)
//
#include <hip/hip_runtime.h>
#include <math.h>

// MemoryEfficientSVDPlaneProjection  (B=16, N=131072, M=16)
// d_in[0]: points f32 [16][131072][3], d_in[1]: planes f32 [16][16][4]
// d_out: proj f32 [16][131072][3] then displacement f32 [16][131072][3]
// ws: [0,24576) accum double[256][12]; [24576,32768) fits float[256][8];
//     [65536, 65536+4MiB) maskbits uint16[16*131072]
//
// Oracle analysis: ref=np AND jax expected agree (threshold ~2% of max|ref|)
// => both are LAPACK sgesdd on the f32 cov. n_ref = Vh[:,:,-1] is the vector
// of z-components of all three singular vectors — sign- and order-sensitive
// in ALL of them. The near-degenerate top pair's final signs depend on the
// QR sweep count, which depends on the f32 deflation thresholds. Therefore:
// emulate sgesdd in f32 with exact f32 SLAMCH constants.

#define NBATCH 16
#define NPTS   131072
#define NPL    16

// ---- f32 LAPACK constants (SLAMCH) ----
#define EPSF  0x1p-24f            // slamch('E') = 5.9604645e-8
#define UNFLF 0x1p-126f           // slamch('S')
#define TOLF  (10.0f * 0x1p-24f)  // tolmul = max(10,min(100,eps^-1/8=8)) = 10

__device__ __forceinline__ void atomAddD(double* addr, double val) {
  unsigned long long* p = (unsigned long long*)addr;
  unsigned long long assumed, old = *p;
  do {
    assumed = old;
    double nv = __longlong_as_double((long long)assumed) + val;
    old = atomicCAS(p, assumed, (unsigned long long)__double_as_longlong(nv));
  } while (old != assumed);
}

// f32 chain matching np einsum 3-term contraction: ((p0*n0 + p1*n1) + p2*n2)
__device__ __forceinline__ float dot3f(float p0, float p1, float p2,
                                       float n0, float n1, float n2) {
  return __fadd_rn(__fadd_rn(__fmul_rn(p0, n0), __fmul_rn(p1, n1)),
                   __fmul_rn(p2, n2));
}

// ---------------- kernel A: mask + f64 moment accumulation ----------------
__global__ __launch_bounds__(256) void k_accum(const float* __restrict__ pts,
                                               const float* __restrict__ planes,
                                               double* __restrict__ accum,
                                               unsigned short* __restrict__ maskbits) {
  const int b = blockIdx.y;
  __shared__ float sn[NPL][4];
  __shared__ int   sval[NPL];
  const int t = threadIdx.x;
  if (t < NPL) {
    const float* pl = planes + (size_t)(b * NPL + t) * 4;
    float x = pl[0], y = pl[1], z = pl[2];
    float nr = sqrtf(__fadd_rn(__fadd_rn(__fmul_rn(x, x), __fmul_rn(y, y)),
                               __fmul_rn(z, z)));
    sval[t] = (nr > 1e-6f) ? 1 : 0;
    float cn = fmaxf(nr, 1e-6f);
    sn[t][0] = x / cn; sn[t][1] = y / cn; sn[t][2] = z / cn;
    sn[t][3] = pl[3];
  }
  __syncthreads();

  const float* pb = pts + (size_t)b * NPTS * 3;
  const int base = blockIdx.x * 2048;
  float P[8][3];
  unsigned int bits8[8];
#pragma unroll
  for (int k = 0; k < 8; ++k) {
    const int n = base + k * 256 + t;
    P[k][0] = pb[n * 3 + 0];
    P[k][1] = pb[n * 3 + 1];
    P[k][2] = pb[n * 3 + 2];
    unsigned int bits = 0;
#pragma unroll
    for (int m = 0; m < NPL; ++m) {
      float s = dot3f(P[k][0], P[k][1], P[k][2], sn[m][0], sn[m][1], sn[m][2]);
      float d = fabsf(__fadd_rn(s, sn[m][3]));
      if (d < 0.015f && sval[m]) bits |= (1u << m);
    }
    bits8[k] = bits;
    maskbits[(size_t)b * NPTS + n] = (unsigned short)bits;
  }

  const int lane = t & 63;
  for (int m = 0; m < NPL; ++m) {
    double s[10];
#pragma unroll
    for (int j = 0; j < 10; ++j) s[j] = 0.0;
#pragma unroll
    for (int k = 0; k < 8; ++k) {
      if ((bits8[k] >> m) & 1u) {
        double p0 = (double)P[k][0], p1 = (double)P[k][1], p2 = (double)P[k][2];
        s[0] += 1.0;
        s[1] += p0; s[2] += p1; s[3] += p2;
        s[4] += p0 * p0; s[5] += p0 * p1; s[6] += p0 * p2;
        s[7] += p1 * p1; s[8] += p1 * p2; s[9] += p2 * p2;
      }
    }
#pragma unroll
    for (int j = 0; j < 10; ++j) {
      double v = s[j];
      v += __shfl_xor(v, 1);
      v += __shfl_xor(v, 2);
      v += __shfl_xor(v, 4);
      v += __shfl_xor(v, 8);
      v += __shfl_xor(v, 16);
      v += __shfl_xor(v, 32);
      if (lane == 0 && v != 0.0) atomAddD(&accum[(b * NPL + m) * 12 + j], v);
    }
  }
}

// ======================= LAPACK sgesdd emulation (3x3, f32) ==================
__device__ __forceinline__ float s_sign(float a, float b) {
  return copysignf(fabsf(a), b);  // Fortran SIGN (IEEE sign-bit semantics)
}

// LAPACK >= 3.10 slartg: c >= 0, r = sign(f)*hypot(f,g)
__device__ void slartg_(float f, float g, float* cs, float* sn, float* r) {
  if (g == 0.0f) { *cs = 1.0f; *sn = 0.0f; *r = f; }
  else if (f == 0.0f) { *cs = 0.0f; *sn = s_sign(1.0f, g); *r = fabsf(g); }
  else {
    float dd = sqrtf(f * f + g * g);
    *cs = fabsf(f) / dd;
    *r = s_sign(dd, f);
    *sn = g / (*r);
  }
}

__device__ void slas2_(float f, float g, float h, float* ssmin, float* ssmax) {
  float fa = fabsf(f), ga = fabsf(g), ha = fabsf(h);
  float fhmn = fminf(fa, ha), fhmx = fmaxf(fa, ha);
  if (fhmn == 0.0f) {
    *ssmin = 0.0f;
    if (fhmx == 0.0f) *ssmax = ga;
    else {
      float mx = fmaxf(fhmx, ga), mn = fminf(fhmx, ga);
      float q = mn / mx;
      *ssmax = mx * sqrtf(1.0f + q * q);
    }
    return;
  }
  if (ga < fhmx) {
    float as_ = 1.0f + fhmn / fhmx;
    float at = (fhmx - fhmn) / fhmx;
    float au = (ga / fhmx); au = au * au;
    float c = 2.0f / (sqrtf(as_ * as_ + au) + sqrtf(at * at + au));
    *ssmin = fhmn * c;
    *ssmax = fhmx / c;
  } else {
    float au = fhmx / ga;
    if (au == 0.0f) { *ssmin = (fhmn * fhmx) / ga; *ssmax = ga; }
    else {
      float as_ = 1.0f + fhmn / fhmx;
      float at = (fhmx - fhmn) / fhmx;
      float t1 = as_ * au, t2 = at * au;
      float c = 1.0f / (sqrtf(1.0f + t1 * t1) + sqrtf(1.0f + t2 * t2));
      float sm = (fhmn * c) * au;
      *ssmin = sm + sm;
      *ssmax = ga / (c + c);
    }
  }
}

__device__ void slasv2_(float f, float g, float h,
                        float* ssmin, float* ssmax,
                        float* snr, float* csr, float* snl, float* csl) {
  float ft = f, fa = fabsf(f), ht = h, ha = fabsf(h);
  int pmax = 1;
  bool swap = (ha > fa);
  if (swap) {
    pmax = 3;
    float tmp = ft; ft = ht; ht = tmp;
    tmp = fa; fa = ha; ha = tmp;
  }
  float gt = g, ga = fabsf(gt);
  float clt = 1.0f, crt = 1.0f, slt = 0.0f, srt = 0.0f;
  if (ga == 0.0f) {
    *ssmin = ha; *ssmax = fa;
  } else {
    bool gasmal = true;
    if (ga > fa) {
      pmax = 2;
      if ((fa / ga) < EPSF) {
        gasmal = false;
        *ssmax = ga;
        if (ha > 1.0f) *ssmin = fa / (ga / ha);
        else *ssmin = (fa / ga) * ha;
        clt = 1.0f; slt = ht / gt;
        srt = 1.0f; crt = ft / gt;
      }
    }
    if (gasmal) {
      float dd = fa - ha;
      float l = (dd == fa) ? 1.0f : dd / fa;
      float mm_ = gt / ft;
      float t = 2.0f - l;
      float mm2 = mm_ * mm_, tt = t * t;
      float s = sqrtf(tt + mm2);
      float r_ = (l == 0.0f) ? fabsf(mm_) : sqrtf(l * l + mm2);
      float a = 0.5f * (s + r_);
      *ssmin = ha / a;
      *ssmax = fa * a;
      if (mm2 == 0.0f) {
        if (l == 0.0f) t = s_sign(2.0f, ft) * s_sign(1.0f, gt);
        else t = gt / s_sign(dd, ft) + mm_ / t;
      } else {
        t = (mm_ / (s + t) + mm_ / (r_ + l)) * (1.0f + a);
      }
      float l2 = sqrtf(t * t + 4.0f);
      crt = 2.0f / l2;
      srt = t / l2;
      clt = (crt + srt * mm_) / a;
      slt = (ht / ft) * srt / a;
    }
  }
  if (swap) { *csl = srt; *snl = crt; *csr = slt; *snr = clt; }
  else { *csl = clt; *snl = slt; *csr = crt; *snr = srt; }
  float tsign = 1.0f;
  if (pmax == 1) tsign = s_sign(1.0f, *csr) * s_sign(1.0f, *csl) * s_sign(1.0f, f);
  if (pmax == 2) tsign = s_sign(1.0f, *snr) * s_sign(1.0f, *csl) * s_sign(1.0f, g);
  if (pmax == 3) tsign = s_sign(1.0f, *snr) * s_sign(1.0f, *snl) * s_sign(1.0f, h);
  *ssmax = s_sign(*ssmax, tsign);
  *ssmin = s_sign(*ssmin, tsign * s_sign(1.0f, f) * s_sign(1.0f, h));
}

// sbdsqr, n=3 upper bidiagonal: d[1..3], e[1..2], vt rows updated (f32).
__device__ void bdsqr3f_(float* d, float* e, float vt[3][3]) {
  const int n = 3;
  float mu = fabsf(d[1]);
  float sminoa = mu;
  for (int i = 2; i <= n && sminoa > 0.0f; ++i) {
    mu = fabsf(d[i]) * (mu / (mu + fabsf(e[i - 1])));
    sminoa = fminf(sminoa, mu);
  }
  sminoa /= sqrtf(3.0f);
  float thresh = fmaxf(TOLF * sminoa, 54.0f * UNFLF);

  int m = n, oldll = -1, oldm = -1, idir = 0;
  int iter = 0;
  const int maxit = 54;
  while (m > 1) {
    if (iter > maxit) break;
    float smax = fabsf(d[m]);
    int ll = 0;
    bool split = false;
    for (int lll = m - 1; lll >= 1; --lll) {
      ll = lll;
      float abss = fabsf(d[ll]), abse = fabsf(e[ll]);
      if (abse <= thresh) { e[ll] = 0.0f; split = true; break; }
      smax = fmaxf(smax, fmaxf(abss, abse));
    }
    if (split) {
      if (ll == m - 1) { m = m - 1; continue; }
      ll = ll + 1;
    } else {
      ll = 1;
    }
    if (ll == m - 1) {
      float sigmn, sigmx, sinr, cosr, sinl, cosl;
      slasv2_(d[m - 1], e[m - 1], d[m], &sigmn, &sigmx, &sinr, &cosr, &sinl, &cosl);
      d[m - 1] = sigmx; d[m] = sigmn; e[m - 1] = 0.0f;
      for (int k = 0; k < 3; ++k) {
        float x = vt[m - 2][k], y = vt[m - 1][k];
        vt[m - 2][k] = cosr * x + sinr * y;
        vt[m - 1][k] = cosr * y - sinr * x;
      }
      m -= 2;
      continue;
    }
    if (ll > oldm || m < oldll) idir = (fabsf(d[ll]) >= fabsf(d[m])) ? 1 : 2;
    float sminl = 0.0f;
    bool cont = false;
    if (idir == 1) {
      if (fabsf(e[m - 1]) <= TOLF * fabsf(d[m])) { e[m - 1] = 0.0f; cont = true; }
      else {
        float mu2 = fabsf(d[ll]); sminl = mu2;
        for (int lll = ll; lll <= m - 1; ++lll) {
          if (fabsf(e[lll]) <= TOLF * mu2) { e[lll] = 0.0f; cont = true; break; }
          mu2 = fabsf(d[lll + 1]) * (mu2 / (mu2 + fabsf(e[lll])));
          sminl = fminf(sminl, mu2);
        }
      }
    } else {
      if (fabsf(e[ll]) <= TOLF * fabsf(d[ll])) { e[ll] = 0.0f; cont = true; }
      else {
        float mu2 = fabsf(d[m]); sminl = mu2;
        for (int lll = m - 1; lll >= ll; --lll) {
          if (fabsf(e[lll]) <= TOLF * mu2) { e[lll] = 0.0f; cont = true; break; }
          mu2 = fabsf(d[lll]) * (mu2 / (mu2 + fabsf(e[lll])));
          sminl = fminf(sminl, mu2);
        }
      }
    }
    if (cont) continue;
    oldll = ll; oldm = m;
    float shift = 0.0f, rr;
    if (!(3.0f * TOLF * (sminl / smax) <= fmaxf(EPSF, 0.01f * TOLF))) {
      float sll;
      if (idir == 1) { sll = fabsf(d[ll]); slas2_(d[m - 1], e[m - 1], d[m], &shift, &rr); }
      else { sll = fabsf(d[m]); slas2_(d[ll], e[ll], d[ll + 1], &shift, &rr); }
      if (sll > 0.0f) {
        float q = shift / sll;
        if (q * q < EPSF) shift = 0.0f;
      }
    }
    iter += m - ll;
    float rc[4], rs[4];
    if (shift == 0.0f) {
      if (idir == 1) {
        float cs = 1.0f, oldcs = 1.0f, sn = 0.0f, oldsn = 0.0f, r2;
        for (int i = ll; i <= m - 1; ++i) {
          slartg_(d[i] * cs, e[i], &cs, &sn, &r2);
          if (i > ll) e[i - 1] = oldsn * r2;
          slartg_(oldcs * r2, d[i + 1] * sn, &oldcs, &oldsn, &d[i]);
          rc[i] = cs; rs[i] = sn;
        }
        float h2 = d[m] * cs;
        d[m] = h2 * oldcs;
        e[m - 1] = h2 * oldsn;
        for (int i = ll; i <= m - 1; ++i)
          for (int k = 0; k < 3; ++k) {
            float x = vt[i - 1][k], y = vt[i][k];
            vt[i - 1][k] = rc[i] * x + rs[i] * y;
            vt[i][k] = rc[i] * y - rs[i] * x;
          }
        if (fabsf(e[m - 1]) <= thresh) e[m - 1] = 0.0f;
      } else {
        float cs = 1.0f, oldcs = 1.0f, sn = 0.0f, oldsn = 0.0f, r2;
        for (int i = m; i >= ll + 1; --i) {
          slartg_(d[i] * cs, e[i - 1], &cs, &sn, &r2);
          if (i < m) e[i] = oldsn * r2;
          slartg_(oldcs * r2, d[i - 1] * sn, &oldcs, &oldsn, &d[i]);
          rc[i] = oldcs; rs[i] = -oldsn;
        }
        float h2 = d[ll] * cs;
        d[ll] = h2 * oldcs;
        e[ll] = h2 * oldsn;
        for (int i = m; i >= ll + 1; --i)
          for (int k = 0; k < 3; ++k) {
            float x = vt[i - 2][k], y = vt[i - 1][k];
            vt[i - 2][k] = rc[i] * x + rs[i] * y;
            vt[i - 1][k] = rc[i] * y - rs[i] * x;
          }
        if (fabsf(e[ll]) <= thresh) e[ll] = 0.0f;
      }
    } else {
      if (idir == 1) {
        float ff = (fabsf(d[ll]) - shift) * (s_sign(1.0f, d[ll]) + shift / d[ll]);
        float gg = e[ll];
        float cosr, sinr, cosl, sinl, r2;
        for (int i = ll; i <= m - 1; ++i) {
          slartg_(ff, gg, &cosr, &sinr, &r2);
          if (i > ll) e[i - 1] = r2;
          ff = cosr * d[i] + sinr * e[i];
          e[i] = cosr * e[i] - sinr * d[i];
          gg = sinr * d[i + 1];
          d[i + 1] = cosr * d[i + 1];
          slartg_(ff, gg, &cosl, &sinl, &r2);
          d[i] = r2;
          ff = cosl * e[i] + sinl * d[i + 1];
          d[i + 1] = cosl * d[i + 1] - sinl * e[i];
          if (i < m - 1) {
            gg = sinl * e[i + 1];
            e[i + 1] = cosl * e[i + 1];
          }
          rc[i] = cosr; rs[i] = sinr;
        }
        e[m - 1] = ff;
        for (int i = ll; i <= m - 1; ++i)
          for (int k = 0; k < 3; ++k) {
            float x = vt[i - 1][k], y = vt[i][k];
            vt[i - 1][k] = rc[i] * x + rs[i] * y;
            vt[i][k] = rc[i] * y - rs[i] * x;
          }
        if (fabsf(e[m - 1]) <= thresh) e[m - 1] = 0.0f;
      } else {
        float ff = (fabsf(d[m]) - shift) * (s_sign(1.0f, d[m]) + shift / d[m]);
        float gg = e[m - 1];
        float cosr, sinr, cosl, sinl, r2;
        for (int i = m; i >= ll + 1; --i) {
          slartg_(ff, gg, &cosr, &sinr, &r2);
          if (i < m) e[i] = r2;
          ff = cosr * d[i] + sinr * e[i - 1];
          e[i - 1] = cosr * e[i - 1] - sinr * d[i];
          gg = sinr * d[i - 1];
          d[i - 1] = cosr * d[i - 1];
          slartg_(ff, gg, &cosl, &sinl, &r2);
          d[i] = r2;
          ff = cosl * e[i - 1] + sinl * d[i - 1];
          d[i - 1] = cosl * d[i - 1] - sinl * e[i - 1];
          if (i > ll + 1) {
            gg = sinl * e[i - 2];
            e[i - 2] = cosl * e[i - 2];
          }
          rc[i] = cosl; rs[i] = -sinl;
        }
        e[ll] = ff;
        if (fabsf(e[ll]) <= thresh) e[ll] = 0.0f;
        for (int i = m; i >= ll + 1; --i)
          for (int k = 0; k < 3; ++k) {
            float x = vt[i - 2][k], y = vt[i - 1][k];
            vt[i - 2][k] = rc[i] * x + rs[i] * y;
            vt[i - 1][k] = rc[i] * y - rs[i] * x;
          }
      }
    }
  }
  for (int i = 1; i <= n; ++i) {
    if (d[i] < 0.0f) {
      d[i] = -d[i];
      for (int k = 0; k < 3; ++k) vt[i - 1][k] = -vt[i - 1][k];
    }
  }
  for (int i = 1; i <= n - 1; ++i) {
    int isub = 1;
    float smin2 = d[1];
    for (int j = 2; j <= n + 1 - i; ++j)
      if (d[j] <= smin2) { isub = j; smin2 = d[j]; }
    int tgt = n + 1 - i;
    if (isub != tgt) {
      float tmp = d[isub]; d[isub] = d[tgt]; d[tgt] = tmp;
      for (int k = 0; k < 3; ++k) {
        float t2 = vt[isub - 1][k]; vt[isub - 1][k] = vt[tgt - 1][k]; vt[tgt - 1][k] = t2;
      }
    }
  }
}

// ---------------- kernel B: per-(b,m) plane fit (f32 sgesdd) ----------------
__global__ __launch_bounds__(256) void k_fit(const double* __restrict__ accum,
                                             float* __restrict__ fits) {
  const int t = threadIdx.x;  // 0..255 == b*16+m
  if (t >= NBATCH * NPL) return;
  const double* a = accum + t * 12;
  const double cnt = a[0];
  float fn0 = 0.f, fn1 = 0.f, fn2 = 0.f, fdr = 0.f, fok = 0.f;
  if (cnt >= 3.0) {
    const double dn = cnt;
    const double c0d = a[1] / dn, c1d = a[2] / dn, c2d = a[3] / dn;
    // cov in f64 (exact one-pass), rounded once to f32, then +1e-8f eye in f32
    // (matches the reference's op order: f32 cov, then + EPS_COV * eye)
    float A[3][3];
    A[0][0] = __fadd_rn((float)(a[4] / dn - c0d * c0d), 1e-8f);
    A[0][1] = (float)(a[5] / dn - c0d * c1d);
    A[0][2] = (float)(a[6] / dn - c0d * c2d);
    A[1][1] = __fadd_rn((float)(a[7] / dn - c1d * c1d), 1e-8f);
    A[1][2] = (float)(a[8] / dn - c1d * c2d);
    A[2][2] = __fadd_rn((float)(a[9] / dn - c2d * c2d), 1e-8f);
    A[1][0] = A[0][1]; A[2][0] = A[0][2]; A[2][1] = A[1][2];

    // ---- sgebd2 (3x3 unblocked, slarfg convention), f32 ----
    float d[4], e[3];
    float alpha = A[0][0];
    float xn = sqrtf(A[1][0] * A[1][0] + A[2][0] * A[2][0]);
    float tauq1 = 0.0f, v2 = 0.0f, v3 = 0.0f;
    if (xn != 0.0f) {
      float beta = -s_sign(sqrtf(alpha * alpha + xn * xn), alpha);
      tauq1 = (beta - alpha) / beta;
      float inv = 1.0f / (alpha - beta);
      v2 = A[1][0] * inv; v3 = A[2][0] * inv;
      alpha = beta;
    }
    d[1] = alpha;
    for (int j = 1; j < 3; ++j) {
      float wv = (A[0][j] + v2 * A[1][j] + v3 * A[2][j]) * tauq1;
      A[0][j] -= wv; A[1][j] -= wv * v2; A[2][j] -= wv * v3;
    }
    alpha = A[0][1];
    xn = fabsf(A[0][2]);
    float taup1 = 0.0f, w2 = 0.0f;
    if (xn != 0.0f) {
      float beta = -s_sign(sqrtf(alpha * alpha + xn * xn), alpha);
      taup1 = (beta - alpha) / beta;
      w2 = A[0][2] / (alpha - beta);
      alpha = beta;
    }
    e[1] = alpha;
    for (int i = 1; i < 3; ++i) {
      float wv = (A[i][1] + w2 * A[i][2]) * taup1;
      A[i][1] -= wv; A[i][2] -= wv * w2;
    }
    alpha = A[1][1];
    xn = fabsf(A[2][1]);
    float tauq2 = 0.0f, u2 = 0.0f;
    if (xn != 0.0f) {
      float beta = -s_sign(sqrtf(alpha * alpha + xn * xn), alpha);
      tauq2 = (beta - alpha) / beta;
      u2 = A[2][1] / (alpha - beta);
      alpha = beta;
    }
    d[2] = alpha;
    {
      float wv = (A[1][2] + u2 * A[2][2]) * tauq2;
      A[1][2] -= wv; A[2][2] -= wv * u2;
    }
    e[2] = A[1][2];
    d[3] = A[2][2];

    // VT0 = P^T = G1 = I - taup1 * w w^T, w = (0, 1, w2)
    float vt[3][3];
    vt[0][0] = 1.0f; vt[0][1] = 0.0f; vt[0][2] = 0.0f;
    vt[1][0] = 0.0f; vt[2][0] = 0.0f;
    vt[1][1] = 1.0f - taup1;
    vt[1][2] = -taup1 * w2;
    vt[2][1] = -taup1 * w2;
    vt[2][2] = 1.0f - taup1 * w2 * w2;

    bdsqr3f_(d, e, vt);

    // n_ref = Vh[:, -1] = VT column 2. (Reference's global sign-flip vs the
    // input normal is exactly output-invariant: every downstream op is odd
    // in n_ref and IEEE rounding is sign-symmetric -> skipped.)
    float r0 = vt[0][2], r1 = vt[1][2], r2v = vt[2][2];
    float cf0 = (float)c0d, cf1 = (float)c1d, cf2 = (float)c2d;
    fdr = -dot3f(cf0, cf1, cf2, r0, r1, r2v);
    fn0 = r0; fn1 = r1; fn2 = r2v; fok = 1.f;
  }
  float* f = fits + t * 8;
  f[0] = fn0; f[1] = fn1; f[2] = fn2; f[3] = fdr; f[4] = fok;
}

// ---------------- kernel C: sequential projection (f32) ----------------
__global__ __launch_bounds__(256) void k_proj(const float* __restrict__ pts,
                                              const float* __restrict__ fits,
                                              const unsigned short* __restrict__ maskbits,
                                              float* __restrict__ out) {
  const int b = blockIdx.y;
  __shared__ float sf[NPL][5];
  const int t = threadIdx.x;
  if (t < NPL) {
    const float* f = fits + (b * NPL + t) * 8;
    sf[t][0] = f[0]; sf[t][1] = f[1]; sf[t][2] = f[2];
    sf[t][3] = f[3]; sf[t][4] = f[4];
  }
  __syncthreads();

  const int n = blockIdx.x * 256 + t;
  const float* pb = pts + (size_t)b * NPTS * 3;
  const float p0 = pb[n * 3 + 0];
  const float p1 = pb[n * 3 + 1];
  const float p2 = pb[n * 3 + 2];
  float q0 = p0, q1 = p1, q2 = p2;
  const unsigned int bits = maskbits[(size_t)b * NPTS + n];
#pragma unroll
  for (int m = 0; m < NPL; ++m) {
    if (((bits >> m) & 1u) && sf[m][4] != 0.f) {
      float s2 = dot3f(q0, q1, q2, sf[m][0], sf[m][1], sf[m][2]);
      float dt = __fadd_rn(s2, sf[m][3]);
      q0 = __fsub_rn(q0, __fmul_rn(sf[m][0], dt));
      q1 = __fsub_rn(q1, __fmul_rn(sf[m][1], dt));
      q2 = __fsub_rn(q2, __fmul_rn(sf[m][2], dt));
    }
  }
  const size_t o = ((size_t)b * NPTS + n) * 3;
  out[o + 0] = q0;
  out[o + 1] = q1;
  out[o + 2] = q2;
  float* disp = out + (size_t)NBATCH * NPTS * 3;
  disp[o + 0] = __fsub_rn(q0, p0);
  disp[o + 1] = __fsub_rn(q1, p1);
  disp[o + 2] = __fsub_rn(q2, p2);
}

extern "C" void kernel_launch(void* const* d_in, const int* in_sizes, int n_in,
                              void* d_out, int out_size, void* d_ws, size_t ws_size,
                              hipStream_t stream) {
  const float* pts    = (const float*)d_in[0];
  const float* planes = (const float*)d_in[1];
  float* out = (float*)d_out;
  double* accum = (double*)d_ws;
  float* fits = (float*)((char*)d_ws + 24576);
  unsigned short* maskbits = (unsigned short*)((char*)d_ws + 65536);

  hipMemsetAsync(d_ws, 0, 24576, stream);
  k_accum<<<dim3(NPTS / 2048, NBATCH), 256, 0, stream>>>(pts, planes, accum, maskbits);
  k_fit<<<1, 256, 0, stream>>>(accum, fits);
  k_proj<<<dim3(NPTS / 256, NBATCH), 256, 0, stream>>>(pts, fits, maskbits, out);
}